// Round 6
// baseline (377.441 us; speedup 1.0000x reference)
//
#include <hip/hip_runtime.h>

#define TGT 100
#define SRC 100
#define KDIM 512
#define HH 256
#define ROWS 1600              // BS*100
#define LOG2E2 2.8853900817779268f   // 2/ln(2): e^(2x) = 2^(LOG2E2*x)
#define NBLK 800               // co-residency proven: <=128 VGPR -> 4 blk/CU cap

typedef __attribute__((ext_vector_type(8))) short bf16x8;
typedef __attribute__((ext_vector_type(4))) float f32x4;

// ws layout: floats [Ek 409600][EqT 409600] then shorts [Apk 1638400][Bpk 262144]
// barrier counters at byte offset 16 MiB (zeroed by on-stream memset each call)
#define EQT_OFF 409600
#define PK_FLOAT_OFF 819200
#define APK_SHORTS 1638400     // 2 mats * 100 rt * 16 kk * 64 lane * 8
#define BAR_BYTE_OFF (16u << 20)

static __device__ __forceinline__ short f2b(float f) {
    union { float f; unsigned u; } v; v.f = f;
    return (short)((v.u + 0x7FFFu + ((v.u >> 16) & 1u)) >> 16);
}

static __device__ __forceinline__ void grid_barrier(unsigned* __restrict__ ctr) {
    __threadfence();           // release my block's global stores (device scope)
    __syncthreads();
    if (threadIdx.x == 0) {
        __hip_atomic_fetch_add(ctr, 1u, __ATOMIC_ACQ_REL, __HIP_MEMORY_SCOPE_AGENT);
        while (__hip_atomic_load(ctr, __ATOMIC_ACQUIRE, __HIP_MEMORY_SCOPE_AGENT) < NBLK)
            __builtin_amdgcn_s_sleep(2);
    }
    __syncthreads();           // block waits on thread 0; L1 is per-CU (shared)
}

// ---------------------------------------------------------------------------
// One kernel, three phases (R5 bodies verbatim), two grid barriers.
// Phase 1 prep : fp32 -> bf16 MFMA-fragment-contiguous packs (Apk, Bpk).
// Phase 2 gemm : 1 wave per 16x16 tile; Ek=exp2(L*keys@Wk), EqT=exp2(L*(q@Wq+b1))^T.
// Phase 3 score: tanh(sumW2 - 2*sum_h W2[h]/(Ek*Eq+1) + b2), s-quad blocks.
// ---------------------------------------------------------------------------
__global__ __launch_bounds__(256, 4) void fused_kernel(
    const float* __restrict__ query, const float* __restrict__ keys,
    const float* __restrict__ Wk, const float* __restrict__ Wq,
    const float* __restrict__ b1, const float* __restrict__ W2,
    const float* __restrict__ B2,
    short* __restrict__ Apk, short* __restrict__ Bpk,
    float* __restrict__ Ek, float* __restrict__ EqT,
    unsigned* __restrict__ bar, float* __restrict__ out)
{
    const int lane = threadIdx.x & 63;
    const int wv = threadIdx.x >> 6;

    // ---------------- Phase 1: pack (grid-stride; pass1 = A, pass2 = B) ----
    for (int i = blockIdx.x * 256 + threadIdx.x; i < 237568; i += NBLK * 256) {
        if (i < 204800) {                     // A-pack: (mat,rt,kk,lane)
            const int ln = i & 63;
            const int rest = i >> 6;          // (mat*100+rt)*16 + kk
            const int kk = rest & 15;
            const int rg = rest >> 4;         // 0..199
            const float* A = (rg >= 100) ? query : keys;
            const int r = (rg % 100) * 16 + (ln & 15);
            const int kb = kk * 32 + (ln >> 4) * 8;
            const float* src = A + (size_t)r * KDIM + kb;
            f32x4 a0 = *(const f32x4*)src;
            f32x4 a1 = *(const f32x4*)(src + 4);
            bf16x8 v;
            #pragma unroll
            for (int j = 0; j < 4; ++j) { v[j] = f2b(a0[j]); v[j + 4] = f2b(a1[j]); }
            *(bf16x8*)(Apk + (size_t)i * 8) = v;
        } else {                              // B-pack: (mat,ht,kk,lane)
            const int t2 = i - 204800;
            const int ln = t2 & 63;
            const int rest = t2 >> 6;         // (mat*16+ht)*16 + kk
            const int kk = rest & 15;
            const int ht = (rest >> 4) & 15;
            const float* W = (rest >> 8) ? Wq : Wk;
            const int kb = kk * 32 + (ln >> 4) * 8;
            const int col = ht * 16 + (ln & 15);
            const float* wp = W + (size_t)kb * HH + col;
            bf16x8 v;
            #pragma unroll
            for (int j = 0; j < 8; ++j) v[j] = f2b(wp[(size_t)j * HH]);
            *(bf16x8*)(Bpk + (size_t)t2 * 8) = v;
        }
    }

    grid_barrier(&bar[0]);

    // ---------------- Phase 2: gemm + exp2 (w = 0..3199, 1 wave/tile) ------
    {
        const int w = blockIdx.x * 4 + wv;
        const int rt = w >> 4;               // 0..199 == mat*100 + rtl
        const int ht = w & 15;
        const int isq = rt >= 100;
        const short* ap = Apk + ((size_t)(rt * 16) * 64 + lane) * 8;
        const short* bp = Bpk + ((size_t)((isq * 16 + ht) * 16) * 64 + lane) * 8;

        f32x4 acc = {0.f, 0.f, 0.f, 0.f};
        #pragma unroll
        for (int kk = 0; kk < 16; ++kk) {
            bf16x8 af = *(const bf16x8*)(ap + (size_t)kk * 512);
            bf16x8 bf = *(const bf16x8*)(bp + (size_t)kk * 512);
            acc = __builtin_amdgcn_mfma_f32_16x16x32_bf16(af, bf, acc, 0, 0, 0);
        }

        const int m = lane & 15, q = lane >> 4;
        const int hc = ht * 16 + m;
        const int r0 = (isq ? rt - 100 : rt) * 16;
        if (!isq) {
            #pragma unroll
            for (int r = 0; r < 4; ++r) {
                const int row = r0 + q * 4 + r;
                Ek[(size_t)row * HH + hc] = __builtin_amdgcn_exp2f(LOG2E2 * acc[r]);
            }
        } else {
            const float bb = b1[hc];
            #pragma unroll
            for (int r = 0; r < 4; ++r) {
                const int row = r0 + q * 4 + r;
                EqT[(size_t)hc * ROWS + row] =
                    __builtin_amdgcn_exp2f(LOG2E2 * (acc[r] + bb));
            }
        }
    }

    grid_barrier(&bar[16]);

    // ---------------- Phase 3: score (bx = 0..799, s-quad per block) -------
    {
        __shared__ float red[4][4][64];
        const int bx = blockIdx.x;
        const int tc = (bx & 1) << 6;        // 0 or 64
        const int g  = bx >> 1;              // 0..399
        const int sq = g % 25;
        const int b  = g / 25;
        const int s0 = sq * 4;
        const int t  = tc + lane;
        const int tcl = t < TGT ? t : TGT - 1;
        const int h0 = wv * 64;

        const float* __restrict__ ek = Ek + (size_t)(b * SRC + s0) * HH + h0;
        const float* __restrict__ eq = EqT + (size_t)h0 * ROWS + (size_t)b * TGT + tcl;
        const float* __restrict__ w2 = W2 + h0;

        float acc0 = 0.f, acc1 = 0.f, acc2 = 0.f, acc3 = 0.f;
        #pragma unroll 4
        for (int hp = 0; hp < 32; ++hp) {
            const int h = hp * 2;
            const float2 w  = *(const float2*)(w2 + h);
            const float  e0 = eq[(size_t)h * ROWS];
            const float  e1 = eq[(size_t)(h + 1) * ROWS];
            const float2 k0 = *(const float2*)(ek + h);
            const float2 k1 = *(const float2*)(ek + HH + h);
            const float2 k2 = *(const float2*)(ek + 2 * HH + h);
            const float2 k3 = *(const float2*)(ek + 3 * HH + h);
            acc0 = fmaf(w.x, __builtin_amdgcn_rcpf(fmaf(k0.x, e0, 1.f)), acc0);
            acc1 = fmaf(w.x, __builtin_amdgcn_rcpf(fmaf(k1.x, e0, 1.f)), acc1);
            acc2 = fmaf(w.x, __builtin_amdgcn_rcpf(fmaf(k2.x, e0, 1.f)), acc2);
            acc3 = fmaf(w.x, __builtin_amdgcn_rcpf(fmaf(k3.x, e0, 1.f)), acc3);
            acc0 = fmaf(w.y, __builtin_amdgcn_rcpf(fmaf(k0.y, e1, 1.f)), acc0);
            acc1 = fmaf(w.y, __builtin_amdgcn_rcpf(fmaf(k1.y, e1, 1.f)), acc1);
            acc2 = fmaf(w.y, __builtin_amdgcn_rcpf(fmaf(k2.y, e1, 1.f)), acc2);
            acc3 = fmaf(w.y, __builtin_amdgcn_rcpf(fmaf(k3.y, e1, 1.f)), acc3);
        }
        red[0][wv][lane] = acc0;
        red[1][wv][lane] = acc1;
        red[2][wv][lane] = acc2;
        red[3][wv][lane] = acc3;
        __syncthreads();

        // wave wv emits output row s0+wv at column t
        float a = red[wv][0][lane] + red[wv][1][lane] + red[wv][2][lane] + red[wv][3][lane];
        float sw = W2[lane] + W2[lane + 64] + W2[lane + 128] + W2[lane + 192];
        #pragma unroll
        for (int off = 32; off; off >>= 1) sw += __shfl_xor(sw, off, 64);
        const float x = sw - 2.f * a + B2[0];
        const float gx = __builtin_amdgcn_exp2f(LOG2E2 * x);
        if (t < TGT)
            out[((size_t)b * SRC + s0 + wv) * TGT + t] =
                1.f - 2.f * __builtin_amdgcn_rcpf(gx + 1.f);
    }
}

extern "C" void kernel_launch(void* const* d_in, const int* in_sizes, int n_in,
                              void* d_out, int out_size, void* d_ws, size_t ws_size,
                              hipStream_t stream) {
    const float* query = (const float*)d_in[0];
    const float* keys  = (const float*)d_in[1];
    const float* Wk    = (const float*)d_in[2];
    const float* Wq    = (const float*)d_in[3];
    const float* b1    = (const float*)d_in[4];
    const float* W2    = (const float*)d_in[5];
    const float* B2    = (const float*)d_in[6];
    float* out = (float*)d_out;

    float* Ek  = (float*)d_ws;
    float* EqT = Ek + EQT_OFF;
    short* Apk = (short*)(Ek + PK_FLOAT_OFF);
    short* Bpk = Apk + APK_SHORTS;
    unsigned* bar = (unsigned*)((char*)d_ws + BAR_BYTE_OFF);

    hipMemsetAsync(bar, 0, 128, stream);   // zero barrier counters (graph-legal)
    fused_kernel<<<NBLK, 256, 0, stream>>>(query, keys, Wk, Wq, b1, W2, B2,
                                           Apk, Bpk, Ek, EqT, bar, out);
}

// Round 7
// 91.336 us; speedup vs baseline: 4.1324x; 4.1324x over previous
//
#include <hip/hip_runtime.h>

#define TGT 100
#define SRC 100
#define KDIM 512
#define HH 256
#define ROWS 1600              // BS*100
#define LOG2E2 2.8853900817779268f   // 2/ln(2): e^(2x) = 2^(LOG2E2*x)

typedef __attribute__((ext_vector_type(8))) short bf16x8;
typedef __attribute__((ext_vector_type(4))) float f32x4;

// ws layout: floats [Ek 409600][EqT 409600] then shorts [Apk 1638400][Bpk 262144]
#define EQT_OFF 409600
#define PK_FLOAT_OFF 819200
#define APK_SHORTS 1638400     // 2 mats * 100 rt * 16 kk * 64 lane * 8

static __device__ __forceinline__ short f2b(float f) {
    union { float f; unsigned u; } v; v.f = f;
    return (short)((v.u + 0x7FFFu + ((v.u >> 16) & 1u)) >> 16);
}

// ---------------------------------------------------------------------------
// Prep: one-shot fp32->bf16 conversion into MFMA-fragment-contiguous layouts.
// Apk[(mat*100+rt)*16+kk][lane][8] : A[m=lane&15][k=kk*32+(lane>>4)*8+j]
// Bpk[(mat*16+ht)*16+kk][lane][8]  : W[k=kk*32+(lane>>4)*8+j][ht*16+(lane&15)]
// Pays the strided W gather + cvt ONCE.
// NOTE (R6): do NOT fuse these phases behind a device-scope grid barrier —
// agent-scope fence/acquire at 800 blocks = per-XCD L2 wb/inv storm, 317 us.
// ---------------------------------------------------------------------------
__global__ __launch_bounds__(256) void prep_kernel(
    const float* __restrict__ query, const float* __restrict__ keys,
    const float* __restrict__ Wk, const float* __restrict__ Wq,
    short* __restrict__ Apk, short* __restrict__ Bpk)
{
    const int tid = blockIdx.x * 256 + threadIdx.x;
    if (tid < 204800) {                       // A-pack: (mat,rt,kk,lane)
        const int lane = tid & 63;
        const int rest = tid >> 6;            // (mat*100+rt)*16 + kk
        const int kk = rest & 15;
        const int rg = rest >> 4;             // mat*100+rt, 0..199
        const float* A = (rg >= 100) ? query : keys;
        const int r = (rg % 100) * 16 + (lane & 15);
        const int kb = kk * 32 + (lane >> 4) * 8;
        const float* src = A + (size_t)r * KDIM + kb;
        f32x4 a0 = *(const f32x4*)src;
        f32x4 a1 = *(const f32x4*)(src + 4);
        bf16x8 v;
        #pragma unroll
        for (int j = 0; j < 4; ++j) { v[j] = f2b(a0[j]); v[j + 4] = f2b(a1[j]); }
        *(bf16x8*)(Apk + (size_t)tid * 8) = v;
    } else if (tid < 237568) {                // B-pack: (mat,ht,kk,lane)
        const int t2 = tid - 204800;
        const int lane = t2 & 63;
        const int rest = t2 >> 6;             // (mat*16+ht)*16 + kk
        const int kk = rest & 15;
        const int ht = (rest >> 4) & 15;
        const float* W = (rest >> 8) ? Wq : Wk;
        const int kb = kk * 32 + (lane >> 4) * 8;
        const int col = ht * 16 + (lane & 15);
        const float* wp = W + (size_t)kb * HH + col;
        bf16x8 v;
        #pragma unroll
        for (int j = 0; j < 8; ++j) v[j] = f2b(wp[(size_t)j * HH]);
        *(bf16x8*)(Bpk + (size_t)t2 * 8) = v;
    }
}

// ---------------------------------------------------------------------------
// GEMM+exp: 1 wave per 16x16 C-tile, 4 waves/block (same rt per block -> L1
// reuse of the A stream). Inner loop = 2 contiguous 1KB bf16x8 loads + MFMA.
//   rt 0..99   : Ek [b*100+s][h]  = exp2(L * keys@Wk)
//   rt 100..199: EqT[h][b*100+t]  = exp2(L * (query@Wq + b1))  (transposed)
// D layout: col=lane&15, row=(lane>>4)*4+reg  (m89/m92-verified).
// ---------------------------------------------------------------------------
__global__ __launch_bounds__(256) void gemm_exp_kernel(
    const short* __restrict__ Apk, const short* __restrict__ Bpk,
    const float* __restrict__ b1,
    float* __restrict__ Ek, float* __restrict__ EqT)
{
    const int lane = threadIdx.x & 63;
    const int w = blockIdx.x * 4 + (threadIdx.x >> 6);   // 0..3199
    const int rt = w >> 4;               // 0..199 == mat*100 + rtl
    const int ht = w & 15;
    const int isq = rt >= 100;
    const short* ap = Apk + ((size_t)(rt * 16) * 64 + lane) * 8;
    const short* bp = Bpk + ((size_t)((isq * 16 + ht) * 16) * 64 + lane) * 8;

    f32x4 acc = {0.f, 0.f, 0.f, 0.f};
    #pragma unroll
    for (int kk = 0; kk < 16; ++kk) {
        bf16x8 af = *(const bf16x8*)(ap + (size_t)kk * 512);
        bf16x8 bf = *(const bf16x8*)(bp + (size_t)kk * 512);
        acc = __builtin_amdgcn_mfma_f32_16x16x32_bf16(af, bf, acc, 0, 0, 0);
    }

    const int m = lane & 15, q = lane >> 4;
    const int hc = ht * 16 + m;
    const int r0 = (isq ? rt - 100 : rt) * 16;
    if (!isq) {
        #pragma unroll
        for (int r = 0; r < 4; ++r) {
            const int row = r0 + q * 4 + r;
            Ek[(size_t)row * HH + hc] = __builtin_amdgcn_exp2f(LOG2E2 * acc[r]);
        }
    } else {
        const float bb = b1[hc];
        #pragma unroll
        for (int r = 0; r < 4; ++r) {
            const int row = r0 + q * 4 + r;
            EqT[(size_t)hc * ROWS + row] =
                __builtin_amdgcn_exp2f(LOG2E2 * (acc[r] + bb));
        }
    }
}

// ---------------------------------------------------------------------------
// Score: score[b][s][t] = tanh(sumW2 - 2*sum_h W2[h]/(Ek[s,h]*Eq[t,h]+1) + b2)
// Block (256 thr) = (b, s-QUAD, 64-t-chunk); each of 4 waves takes a 64-h
// quarter for all 4 s. Per iter: 7 loads covering 512 (s,t,h) elems.
// 4KB LDS reduce; wave w emits output row s0+w. grid = 16*25*2 = 800 blocks.
// ---------------------------------------------------------------------------
__global__ __launch_bounds__(256) void score_kernel(
    const float* __restrict__ Ek, const float* __restrict__ EqT,
    const float* __restrict__ W2, const float* __restrict__ B2,
    float* __restrict__ out)
{
    __shared__ float red[4][4][64];
    const int lane = threadIdx.x & 63;
    const int wv = threadIdx.x >> 6;
    const int bx = blockIdx.x;           // 0..799
    const int tc = (bx & 1) << 6;        // 0 or 64
    const int g  = bx >> 1;              // 0..399
    const int sq = g % 25;
    const int b  = g / 25;
    const int s0 = sq * 4;
    const int t  = tc + lane;
    const int tcl = t < TGT ? t : TGT - 1;
    const int h0 = wv * 64;

    const float* __restrict__ ek = Ek + (size_t)(b * SRC + s0) * HH + h0;
    const float* __restrict__ eq = EqT + (size_t)h0 * ROWS + (size_t)b * TGT + tcl;
    const float* __restrict__ w2 = W2 + h0;

    float acc0 = 0.f, acc1 = 0.f, acc2 = 0.f, acc3 = 0.f;
    #pragma unroll 4
    for (int hp = 0; hp < 32; ++hp) {
        const int h = hp * 2;
        const float2 w  = *(const float2*)(w2 + h);
        const float  e0 = eq[(size_t)h * ROWS];
        const float  e1 = eq[(size_t)(h + 1) * ROWS];
        const float2 k0 = *(const float2*)(ek + h);
        const float2 k1 = *(const float2*)(ek + HH + h);
        const float2 k2 = *(const float2*)(ek + 2 * HH + h);
        const float2 k3 = *(const float2*)(ek + 3 * HH + h);
        acc0 = fmaf(w.x, __builtin_amdgcn_rcpf(fmaf(k0.x, e0, 1.f)), acc0);
        acc1 = fmaf(w.x, __builtin_amdgcn_rcpf(fmaf(k1.x, e0, 1.f)), acc1);
        acc2 = fmaf(w.x, __builtin_amdgcn_rcpf(fmaf(k2.x, e0, 1.f)), acc2);
        acc3 = fmaf(w.x, __builtin_amdgcn_rcpf(fmaf(k3.x, e0, 1.f)), acc3);
        acc0 = fmaf(w.y, __builtin_amdgcn_rcpf(fmaf(k0.y, e1, 1.f)), acc0);
        acc1 = fmaf(w.y, __builtin_amdgcn_rcpf(fmaf(k1.y, e1, 1.f)), acc1);
        acc2 = fmaf(w.y, __builtin_amdgcn_rcpf(fmaf(k2.y, e1, 1.f)), acc2);
        acc3 = fmaf(w.y, __builtin_amdgcn_rcpf(fmaf(k3.y, e1, 1.f)), acc3);
    }
    red[0][wv][lane] = acc0;
    red[1][wv][lane] = acc1;
    red[2][wv][lane] = acc2;
    red[3][wv][lane] = acc3;
    __syncthreads();

    // wave wv emits output row s0+wv at column t
    float a = red[wv][0][lane] + red[wv][1][lane] + red[wv][2][lane] + red[wv][3][lane];
    float sw = W2[lane] + W2[lane + 64] + W2[lane + 128] + W2[lane + 192];
    #pragma unroll
    for (int off = 32; off; off >>= 1) sw += __shfl_xor(sw, off, 64);
    const float x = sw - 2.f * a + B2[0];
    const float gx = __builtin_amdgcn_exp2f(LOG2E2 * x);
    if (t < TGT)
        out[((size_t)b * SRC + s0 + wv) * TGT + t] =
            1.f - 2.f * __builtin_amdgcn_rcpf(gx + 1.f);
}

extern "C" void kernel_launch(void* const* d_in, const int* in_sizes, int n_in,
                              void* d_out, int out_size, void* d_ws, size_t ws_size,
                              hipStream_t stream) {
    const float* query = (const float*)d_in[0];
    const float* keys  = (const float*)d_in[1];
    const float* Wk    = (const float*)d_in[2];
    const float* Wq    = (const float*)d_in[3];
    const float* b1    = (const float*)d_in[4];
    const float* W2    = (const float*)d_in[5];
    const float* B2    = (const float*)d_in[6];
    float* out = (float*)d_out;

    float* Ek  = (float*)d_ws;
    float* EqT = Ek + EQT_OFF;
    short* Apk = (short*)(Ek + PK_FLOAT_OFF);
    short* Bpk = Apk + APK_SHORTS;

    prep_kernel<<<928, 256, 0, stream>>>(query, keys, Wk, Wq, Apk, Bpk);
    gemm_exp_kernel<<<800, 256, 0, stream>>>(Apk, Bpk, b1, Ek, EqT);
    score_kernel<<<800, 256, 0, stream>>>(Ek, EqT, W2, B2, out);
}